// Round 9
// baseline (246.463 us; speedup 1.0000x reference)
//
#include <hip/hip_runtime.h>
#include <hip/hip_bf16.h>

// ---------------- problem constants ----------------
#define HW    4096      // H*W
#define BB    8         // batch
#define TT    8         // time steps

// ws layout (in floats)
constexpr int OFF_WFRAG = 0;                   // 34 frags * 64 lanes * 16B = 8704 floats
constexpr int OFF_WXB   = 12800;               // 256 float2 = 512 floats {w_x, bias}

// gate pre-scales folded into w_hh / w_x / bias at prep time:
//   i,f,o rows: * -log2(e)   -> sigmoid(x) = rcp(exp2(acc)+1)
//   g rows:     * 2*log2(e)  -> tanh(x) = (exp2(acc)-1)/(exp2(acc)+1)
constexpr float SI = -1.44269504088896340736f; // -log2(e)
constexpr float SG =  2.88539008177792681472f; // 2*log2(e)

typedef _Float16 halfx8 __attribute__((ext_vector_type(8)));
typedef _Float16 halfx4 __attribute__((ext_vector_type(4)));
typedef float    floatx4 __attribute__((ext_vector_type(4)));
typedef float    floatx2 __attribute__((ext_vector_type(2)));

__device__ inline float fast_exp2(float x) {
#if __has_builtin(__builtin_amdgcn_exp2f)
    return __builtin_amdgcn_exp2f(x);
#else
    return __builtin_exp2f(x);
#endif
}
__device__ inline float fast_rcp(float x) {
#if __has_builtin(__builtin_amdgcn_rcpf)
    return __builtin_amdgcn_rcpf(x);
#else
    return 1.0f / x;
#endif
}
__device__ inline floatx2 exp2x2(floatx2 x) {
    floatx2 r; r.x = fast_exp2(x.x); r.y = fast_exp2(x.y); return r;
}
// r16: pairwise-batched reciprocal (1 v_rcp + 3 v_mul for 2 rcps). Verified
// pass, absmax unchanged. Perf-neutral (r16 null -> trans ~= mul issue cost)
// but harmless; kept.
__device__ inline floatx2 rcpx2(floatx2 x) {
    float R = fast_rcp(x.x * x.y);
    floatx2 r; r.x = R * x.y; r.y = R * x.x; return r;
}

union pack8 { _Float16 h[8]; uint4 u; };

// ---------------- prep: repack weights into d_ws (10 blocks) ----------------
// r9: folds activation pre-scales (SI/SG) into the f16 B-fragments and the
// {w_x,bias} table. r11: gate-column permutation (thread (s,hb) produces
// hid = 4s+hb -> b64-packed h-writes). Unchanged since r13.
__global__ __launch_bounds__(256) void prep_kernel(
    const float* __restrict__ w_ih,  const float* __restrict__ w_hh,
    const float* __restrict__ b_ih,  const float* __restrict__ b_hh,
    const float* __restrict__ w_s,   const float* __restrict__ w_out,
    float* __restrict__ ws_f) {
    int tid = threadIdx.x;
    int bid = blockIdx.x;
    if (bid < 9) {
        int e = bid * 256 + tid;
        uint4* wf = (uint4*)(ws_f + OFF_WFRAG);
        if (e < 2048) {
            int l  = e & 63;
            int fi = e >> 6;
            int nb = fi >> 1, kc = fi & 1;
            int hb = nb & 3, gi = nb >> 2;
            int gate = gi * 64 + 4 * (l & 15) + hb;   // r11 permuted column
            int hid  = kc * 32 + (l >> 4) * 8;
            float sc = (gi == 2) ? SG : SI;
            const float* src = w_hh + gate * 64 + hid;
            pack8 p;
            #pragma unroll
            for (int j = 0; j < 8; ++j) p.h[j] = (_Float16)(src[j] * sc);
            wf[e] = p.u;
        } else if (e < 2176) {
            // s-projection fragments (frags 32,33): B[k][0]=w_s[k] (UNSCALED)
            int t2 = e - 2048;
            int l = t2 & 63, kc = t2 >> 6;
            pack8 p;
            #pragma unroll
            for (int j = 0; j < 8; ++j) p.h[j] = (_Float16)0.0f;
            if ((l & 15) == 0) {
                #pragma unroll
                for (int j = 0; j < 8; ++j)
                    p.h[j] = (_Float16)w_s[kc * 32 + (l >> 4) * 8 + j];
            }
            wf[e] = p.u;
        }
    } else {
        // {w_x, bias} pairs, permuted + pre-scaled.
        int s_ = tid & 15, hb = (tid >> 4) & 3, gi = tid >> 6;
        int gate = gi * 64 + 4 * s_ + hb;
        float sc = (gi == 2) ? SG : SI;
        floatx2 v; v.x = w_ih[gate] * sc; v.y = (b_ih[gate] + b_hh[gate]) * sc;
        ((floatx2*)(ws_f + OFF_WXB))[tid] = v;
    }
}

// ---------------- fully fused conv_in + LSTM + conv_out ----------------
// r17 OCCUPANCY DOUBLING. r16 diagnosis: VALU ~66% and LDS pipe ~65% are
// co-limiting, neither saturated -> TLP-starved at 16 waves/CU, pinned by
// LDS capacity only (VGPR 52 <= 64 allows 2048 thr/CU). Changes (ALL
// layout-only, arithmetic identical to r16):
//  - Block = 1024 threads = 16 waves = TWO 16-px tiles x 8 groups; one
//    shared wfrag copy (the 34816 B duplication was the occupancy blocker).
//  - x_lds/stile MERGED (identical index (g*8+t)*16+px; slot (g,t') is
//    last-read as x at iter t', first-written as s at iter t'+1). hin
//    staging relocated into h_lds (dead region until zeroed).
//  - h state 72->64-wide with 16B-granule XOR swizzle (block ^= row&7):
//    phys(hid,row) = 8*((hid>>3)^(row&7)) + (hid&7). A-reads uniform
//    (8 lanes/16B-slot); b64 h-writes <= 2-way. Replaces the +8 pad.
//  - wt_lds dropped: w_in/w_out read direct from global (one-time,
//    L1-broadcast across the 16 lanes sharing each address).
// LDS = 34816(wfrag) + 32768(h,16 waves) + 8192(x/stile) + 2048(wxb)
//     = 77824 <= 81920 -> 2 blocks/CU = 32 waves/CU (needs VGPR <= 64;
//    kill-criterion: VGPR>64 or occ<=50% -> revert).
// asm clobber STAYS (r7/r12: reg-caching LDS crosses the VGPR cliff).
__global__ __launch_bounds__(1024) void lstm_kernel(
    const float* __restrict__ hin,    // (B, 64, HW) original input h
    const float* __restrict__ ws_f,   // tables
    float* __restrict__ out,          // (B, 64, HW) final output
    const float* __restrict__ w_in,   // (64, 64)
    const float* __restrict__ b_in,   // (64,)
    const float* __restrict__ b_s_p,  // (1,)
    const float* __restrict__ b_out,  // (64,)
    const float* __restrict__ w_out) {// (64, 64) [o][c]
    __shared__ uint4 wfrag_lds[2176];                  // 34816 B
    __shared__ floatx2 wxb_lds[256];                   // 2048 B
    __shared__ __align__(16) float xs_buf[2048];       // 8192 B: [2 tiles][c=g*8+t][px16]
    __shared__ __align__(16) _Float16 h_lds[16384];    // 32768 B: 16 waves x 16 x 64 swz
                                                       //          (first 8192 B: hin stage)

    int tid = threadIdx.x;
    int lane = tid & 63;
    int wv   = tid >> 6;                  // 0..15
    int tl   = wv >> 3;                   // tile 0/1
    int g    = wv & 7;                    // group
    int s    = lane & 15;                 // seq-local == pixel-local
    int q    = lane >> 4;

    int gt = blockIdx.x * 2 + tl;         // global tile id (0..2047)
    int b  = gt >> 8;
    int p0 = (gt & 255) * 16;

    // ---- stage weight fragments (shared by all 16 waves)
    const uint4* wfg = (const uint4*)(ws_f + OFF_WFRAG);
    #pragma unroll
    for (int i = 0; i < 3; ++i) {
        int e = tid + 1024 * i;
        if (e < 2176) wfrag_lds[e] = wfg[e];
    }
    if (tid < 256) wxb_lds[tid] = ((const floatx2*)(ws_f + OFF_WXB))[tid];
    // stage hin tiles (2 x 64 ch x 16 px) into h_lds-front (dead until zeroed)
    if (tid < 512) {
        int tls = tid >> 8, cc = (tid >> 2) & 63, f4 = tid & 3;
        int gts = blockIdx.x * 2 + tls;
        int bs_ = gts >> 8, p0s = (gts & 255) * 16;
        ((floatx4*)h_lds)[tid] =
            *(const floatx4*)&hin[(bs_ * 64 + cc) * HW + p0s + f4 * 4];
    }
    __syncthreads();

    // ---- conv_in (per wave, own tile+group):
    // x[g][t][px] = sum_c w_in[g8+t][c]*hin[c][px] + b_in   (w_in from global)
    float* xs = xs_buf + tl * 1024 + g * 128;   // [t][px] region, = stile rows g*8+t
    {
        const float* hin_st = (const float*)h_lds + tl * 1024;
        const float* wrow0 = w_in + (g * 8 + q) * 64;
        const float* wrow1 = w_in + (g * 8 + q + 4) * 64;
        floatx2 xacc; xacc.x = b_in[g * 8 + q]; xacc.y = b_in[g * 8 + q + 4];
        #pragma unroll 8
        for (int cc = 0; cc < 64; ++cc) {
            float hv = hin_st[cc * 16 + s];
            xacc.x += wrow0[cc] * hv;
            xacc.y += wrow1[cc] * hv;
        }
        xs[q * 16 + s]       = xacc.x;
        xs[(q + 4) * 16 + s] = xacc.y;
    }
    __syncthreads();   // all hin reads complete before h zero
    // zero h state (8192 u32)
    #pragma unroll
    for (int i = 0; i < 8; ++i)
        ((unsigned*)h_lds)[tid + 1024 * i] = 0u;
    __syncthreads();

    _Float16* hrow = h_lds + wv * 1024;   // 16 rows x 64 (swizzled)
    float bs = b_s_p[0];
    int sh8 = (s >> 1);                   // h-write 16B-block base
    int so4 = 4 * (s & 1);                // within-block offset

    // c-state, stored PRE-SCALED by 2*log2(e)
    float c_st[4][4];
    #pragma unroll
    for (int hb = 0; hb < 4; ++hb)
        #pragma unroll
        for (int r = 0; r < 4; ++r) c_st[hb][r] = 0.0f;

    for (int t = 0; t < TT; ++t) {
        // Memory barrier: forbids caching LDS (frags/wxb/x/h) in registers
        // across iterations (r7/r12: caching balloons regs past the cliff).
        asm volatile("" ::: "memory");

        // A-frags, swizzled: h[s][k], block k>>3 XOR'd with s&7
        halfx8 a0 = *(const halfx8*)(hrow + s * 64 + 8 * (q ^ (s & 7)));
        halfx8 a1 = *(const halfx8*)(hrow + s * 64 + 8 * ((q + 4) ^ (s & 7)));

        // s_{t-1} = h_t @ w_s via MFMA (col 0 only); lanes s==0 hold seq q*4+r
        if (t > 0) {
            halfx8 sb0 = *(const halfx8*)&wfrag_lds[32 * 64 + lane];
            halfx8 sb1 = *(const halfx8*)&wfrag_lds[33 * 64 + lane];
            floatx4 sa = {0.f, 0.f, 0.f, 0.f};
            sa = __builtin_amdgcn_mfma_f32_16x16x32_f16(a0, sb0, sa, 0, 0, 0);
            sa = __builtin_amdgcn_mfma_f32_16x16x32_f16(a1, sb1, sa, 0, 0, 0);
            if (s == 0) {
                floatx4 o4 = {sa[0] + bs, sa[1] + bs, sa[2] + bs, sa[3] + bs};
                *(floatx4*)&xs[(t - 1) * 16 + q * 4] = o4;   // stile slot g*8+(t-1)
            }
        }

        floatx4 xv = *(const floatx4*)&xs[t * 16 + q * 4];
        floatx2 xlo; xlo.x = xv[0]; xlo.y = xv[1];
        floatx2 xhi; xhi.x = xv[2]; xhi.y = xv[3];

        halfx4 hpack[4];   // per-row packed h (hb-contiguous thanks to r11 perm)

        #pragma unroll
        for (int hb = 0; hb < 4; ++hb) {
            floatx4 acc[4];
            #pragma unroll
            for (int gi = 0; gi < 4; ++gi) {
                int nb = hb + 4 * gi;
                floatx2 wb = wxb_lds[s + 16 * nb];
                floatx2 lo = xlo * wb.x + wb.y;     // x*w_x + bias as C init (pk_fma)
                floatx2 hi = xhi * wb.x + wb.y;
                floatx4 a = {lo.x, lo.y, hi.x, hi.y};
                halfx8 b0 = *(const halfx8*)&wfrag_lds[(nb * 2 + 0) * 64 + lane];
                halfx8 b1 = *(const halfx8*)&wfrag_lds[(nb * 2 + 1) * 64 + lane];
                a = __builtin_amdgcn_mfma_f32_16x16x32_f16(a0, b0, a, 0, 0, 0);
                a = __builtin_amdgcn_mfma_f32_16x16x32_f16(a1, b1, a, 0, 0, 0);
                acc[gi] = a;
            }
            #pragma unroll
            for (int p = 0; p < 2; ++p) {
                int r0 = 2 * p;
                // accs are pre-scaled: Ei=e^-i, Ef=e^-f, Eo=e^-o, Eg=e^{2g}
                floatx2 Ei; Ei.x = fast_exp2(acc[0][r0]); Ei.y = fast_exp2(acc[0][r0 + 1]);
                floatx2 Ef; Ef.x = fast_exp2(acc[1][r0]); Ef.y = fast_exp2(acc[1][r0 + 1]);
                floatx2 Eg; Eg.x = fast_exp2(acc[2][r0]); Eg.y = fast_exp2(acc[2][r0 + 1]);
                floatx2 Eo; Eo.x = fast_exp2(acc[3][r0]); Eo.y = fast_exp2(acc[3][r0 + 1]);
                floatx2 Bf  = Ef + 1.0f;
                floatx2 Pig = (Ei + 1.0f) * (Eg + 1.0f);
                floatx2 cp; cp.x = c_st[hb][r0]; cp.y = c_st[hb][r0 + 1];
                // cs' = f*cs + 2log2e * i*g  ==  [cs*Pig + SG*(Eg-1)*Bf] / (Bf*Pig)
                floatx2 num = cp * Pig + (Eg * SG - SG) * Bf;   // fma: SG*(Eg-1) exact
                floatx2 cs  = num * rcpx2(Bf * Pig);
                c_st[hb][r0] = cs.x; c_st[hb][r0 + 1] = cs.y;
                // h = o*tanh(c) = (Ec-1) / ((1+Eo)(1+Ec)),  Ec = exp2(cs) = e^{2c}
                floatx2 Ec  = exp2x2(cs);
                floatx2 hn  = (Ec - 1.0f) * rcpx2((Eo + 1.0f) * (Ec + 1.0f));
                hpack[r0 + 0][hb] = (_Float16)hn.x;
                hpack[r0 + 1][hb] = (_Float16)hn.y;
            }
        }
        // state for t+1: 4x ds_write_b64 at hid 4s..4s+3, rows q*4+r, swizzled
        {
            int rowb = q * 4;
            #pragma unroll
            for (int r = 0; r < 4; ++r) {
                int row = rowb + r;
                *(halfx4*)(hrow + row * 64 + 8 * (sh8 ^ (row & 7)) + so4) = hpack[r];
            }
        }
    }
    // final s_7 from h_8
    {
        asm volatile("" ::: "memory");
        halfx8 a0 = *(const halfx8*)(hrow + s * 64 + 8 * (q ^ (s & 7)));
        halfx8 a1 = *(const halfx8*)(hrow + s * 64 + 8 * ((q + 4) ^ (s & 7)));
        halfx8 sb0 = *(const halfx8*)&wfrag_lds[32 * 64 + lane];
        halfx8 sb1 = *(const halfx8*)&wfrag_lds[33 * 64 + lane];
        floatx4 sa = {0.f, 0.f, 0.f, 0.f};
        sa = __builtin_amdgcn_mfma_f32_16x16x32_f16(a0, sb0, sa, 0, 0, 0);
        sa = __builtin_amdgcn_mfma_f32_16x16x32_f16(a1, sb1, sa, 0, 0, 0);
        if (s == 0) {
            floatx4 o4 = {sa[0] + bs, sa[1] + bs, sa[2] + bs, sa[3] + bs};
            *(floatx4*)&xs[7 * 16 + q * 4] = o4;
        }
    }
    __syncthreads();   // all stile channels ready

    // ---- conv_out epilogue: out[b][o][p0+px] = sum_c w_out[o][c]*stile[c][px] + b_out[o]
    // (w_out from global; 16 px-lanes share each address -> L1 broadcast)
    {
        int tle = tid >> 9;
        int px  = tid & 15;
        int oo  = (tid >> 4) & 31;         // outputs oo and oo+32
        int gte = blockIdx.x * 2 + tle;
        int be  = gte >> 8, p0e = (gte & 255) * 16;
        const float* st = xs_buf + tle * 1024;
        floatx2 acc; acc.x = b_out[oo]; acc.y = b_out[oo + 32];
        #pragma unroll
        for (int c4 = 0; c4 < 16; ++c4) {
            floatx4 w0 = *(const floatx4*)&w_out[oo * 64 + c4 * 4];
            floatx4 w1 = *(const floatx4*)&w_out[(oo + 32) * 64 + c4 * 4];
            #pragma unroll
            for (int j = 0; j < 4; ++j) {
                float sv = st[(c4 * 4 + j) * 16 + px];
                acc.x += w0[j] * sv;
                acc.y += w1[j] * sv;
            }
        }
        out[(be * 64 + oo) * HW + p0e + px]      = acc.x;
        out[(be * 64 + oo + 32) * HW + p0e + px] = acc.y;
    }
}

extern "C" void kernel_launch(void* const* d_in, const int* in_sizes, int n_in,
                              void* d_out, int out_size, void* d_ws, size_t ws_size,
                              hipStream_t stream) {
    const float* h     = (const float*)d_in[0];
    const float* w_in  = (const float*)d_in[1];
    const float* b_in  = (const float*)d_in[2];
    const float* w_ih  = (const float*)d_in[3];
    const float* w_hh  = (const float*)d_in[4];
    const float* b_ih  = (const float*)d_in[5];
    const float* b_hh  = (const float*)d_in[6];
    const float* w_s   = (const float*)d_in[7];
    const float* b_s   = (const float*)d_in[8];
    const float* w_out = (const float*)d_in[9];
    const float* b_out = (const float*)d_in[10];
    float* out = (float*)d_out;
    float* ws  = (float*)d_ws;

    prep_kernel<<<10, 256, 0, stream>>>(w_ih, w_hh, b_ih, b_hh, w_s, w_out, ws);
    // r17: 1024 blocks x 1024 threads (2 px-tiles x 8 groups per block).
    lstm_kernel<<<1024, 1024, 0, stream>>>(h, ws, out, w_in, b_in, b_s, b_out, w_out);
}

// Round 10
// 232.105 us; speedup vs baseline: 1.0619x; 1.0619x over previous
//
#include <hip/hip_runtime.h>
#include <hip/hip_bf16.h>

// ---------------- problem constants ----------------
#define HW    4096      // H*W
#define BB    8         // batch
#define TT    8         // time steps

// ws layout (in floats)
constexpr int OFF_WFRAG = 0;                   // 32 frags * 64 lanes * 16B = 8192 floats
constexpr int OFF_WXB   = 8192;                // 256 u32 {w_x, bias} f16 pairs

// gate pre-scales folded into w_hh / w_x / bias at prep time:
//   i,f,o rows: * -log2(e)   -> sigmoid(x) = rcp(exp2(acc)+1)
//   g rows:     * 2*log2(e)  -> tanh(x) = (exp2(acc)-1)/(exp2(acc)+1)
constexpr float SI = -1.44269504088896340736f; // -log2(e)
constexpr float SG =  2.88539008177792681472f; // 2*log2(e)

typedef _Float16 halfx8 __attribute__((ext_vector_type(8)));
typedef _Float16 halfx4 __attribute__((ext_vector_type(4)));
typedef float    floatx4 __attribute__((ext_vector_type(4)));
typedef float    floatx2 __attribute__((ext_vector_type(2)));

__device__ inline float fast_exp2(float x) {
#if __has_builtin(__builtin_amdgcn_exp2f)
    return __builtin_amdgcn_exp2f(x);
#else
    return __builtin_exp2f(x);
#endif
}
__device__ inline float fast_rcp(float x) {
#if __has_builtin(__builtin_amdgcn_rcpf)
    return __builtin_amdgcn_rcpf(x);
#else
    return 1.0f / x;
#endif
}
__device__ inline floatx2 exp2x2(floatx2 x) {
    floatx2 r; r.x = fast_exp2(x.x); r.y = fast_exp2(x.y); return r;
}
// r16: pairwise-batched reciprocal (1 v_rcp + 3 v_mul for 2 rcps); verified.
__device__ inline floatx2 rcpx2(floatx2 x) {
    float R = fast_rcp(x.x * x.y);
    floatx2 r; r.x = R * x.y; r.y = R * x.x; return r;
}

union pack8 { _Float16 h[8]; uint4 u; };
union uh2   { unsigned u; _Float16 h[2]; };

// ---------------- prep: repack weights into d_ws (9 blocks) ----------------
// r9: activation pre-scales (SI/SG) folded in. r11: gate-column permutation
// (frag col sc of nb=(hb+4gi) holds gate 64*gi+4*sc+hb -> thread (s,hb)
// produces hid=4s+hb -> b64-packed h-writes).
// r18: s-frags REMOVED from ws (lstm builds sb0/sb1 from global w_s into
// regs); wxb compacted to f16 pairs (bias=b_ih+b_hh is exact here; w_ih f16
// rounding is the same class as the already-f16 w_hh).
__global__ __launch_bounds__(256) void prep_kernel(
    const float* __restrict__ w_ih,  const float* __restrict__ w_hh,
    const float* __restrict__ b_ih,  const float* __restrict__ b_hh,
    float* __restrict__ ws_f) {
    int tid = threadIdx.x;
    int bid = blockIdx.x;
    if (bid < 8) {
        int e = bid * 256 + tid;       // 0..2047
        uint4* wf = (uint4*)(ws_f + OFF_WFRAG);
        int l  = e & 63;
        int fi = e >> 6;
        int nb = fi >> 1, kc = fi & 1;
        int hb = nb & 3, gi = nb >> 2;
        int gate = gi * 64 + 4 * (l & 15) + hb;   // r11 permuted column
        int hid  = kc * 32 + (l >> 4) * 8;
        float sc = (gi == 2) ? SG : SI;
        const float* src = w_hh + gate * 64 + hid;
        pack8 p;
        #pragma unroll
        for (int j = 0; j < 8; ++j) p.h[j] = (_Float16)(src[j] * sc);
        wf[e] = p.u;
    } else {
        // {w_x, bias} f16 pairs, permuted + pre-scaled.
        // read idx = s + 16*hb + 64*gi  ->  gate 64*gi + 4*s + hb
        int s_ = tid & 15, hb = (tid >> 4) & 3, gi = tid >> 6;
        int gate = gi * 64 + 4 * s_ + hb;
        float sc = (gi == 2) ? SG : SI;
        uh2 v;
        v.h[0] = (_Float16)(w_ih[gate] * sc);
        v.h[1] = (_Float16)((b_ih[gate] + b_hh[gate]) * sc);
        ((unsigned*)(ws_f + OFF_WXB))[tid] = v.u;
    }
}

// ---------------- fully fused conv_in + LSTM + conv_out ----------------
// Block = 512 threads = 8 waves = ONE 16-pixel tile x ALL 8 groups.
// r17 POST-MORTEM recalibration: VALUBusy/MfmaUtil are CU-LEVEL (any-SIMD)
// counters; true per-pipe picture at r16 was VALU ~16%/SIMD, MFMA ~5%,
// LDS pipe ~67% (per-CU shared) -> the kernel is LDS-THROUGHPUT-bound with
// a 33% latency/barrier tail. Also: 2x1024-thread blocks would NOT co-reside
// (occ stayed 16 waves/CU) -> big blocks are a dead end; swizzled-h measured
// ZERO bank conflicts; merged x/stile verified bit-exact.
// r18: 3-blocks-per-CU LDS DIET at the known-good 512-thr structure.
// LDS = 54272 B = 53.0 KiB exactly -> 3 blocks = 24 waves/CU (+50% TLP
// against the 67%-busy LDS pipe + latency tail):
//  - wfrag 32 frags (s-frags -> 8 regs from global w_s, safe <=64-reg band)
//  - wxb as f16 pairs (1024 B)
//  - x/stile merged (4096 B), hin staged in h_lds front
//  - h 64-wide XOR-swizzled (16384 B), zero conflicts (r17-measured)
//  - w_in / w_out read direct from global (floatx4, L1-broadcast)
// asm clobber STAYS (r7/r12: reg-caching LDS crosses the VGPR cliff).
__global__ __launch_bounds__(512) void lstm_kernel(
    const float* __restrict__ hin,    // (B, 64, HW) original input h
    const float* __restrict__ ws_f,   // tables
    float* __restrict__ out,          // (B, 64, HW) final output
    const float* __restrict__ w_in,   // (64, 64)
    const float* __restrict__ b_in,   // (64,)
    const float* __restrict__ w_s,    // (1, 64)
    const float* __restrict__ b_s_p,  // (1,)
    const float* __restrict__ b_out,  // (64,)
    const float* __restrict__ w_out) {// (64, 64) [o][c]
    __shared__ uint4 wfrag_lds[2048];                  // 32768 B
    __shared__ unsigned wxb_lds[256];                  // 1024 B
    __shared__ __align__(16) float xs_buf[1024];       // 4096 B: [c=g*8+t][px16] x then s
    __shared__ __align__(16) _Float16 h_lds[8192];     // 16384 B: 8 waves x 16 x 64 swz
                                                       //          (front 4096 B: hin stage)

    int tid = threadIdx.x;
    int ptile = blockIdx.x & 255;         // 256 tiles of 16 px
    int b     = blockIdx.x >> 8;
    int p0 = ptile * 16;

    int lane = tid & 63;
    int wv   = tid >> 6;                  // 0..7 == group g
    int g    = wv;
    int s    = lane & 15;                 // seq-local == pixel-local
    int q    = lane >> 4;

    // ---- stage weight fragments + wxb
    const uint4* wfg = (const uint4*)(ws_f + OFF_WFRAG);
    #pragma unroll
    for (int i = 0; i < 4; ++i)
        wfrag_lds[tid + 512 * i] = wfg[tid + 512 * i];
    if (tid < 256) wxb_lds[tid] = ((const unsigned*)(ws_f + OFF_WXB))[tid];
    // stage hin tile (64 ch x 16 px, f32) into h_lds front (dead until zeroed)
    if (tid < 256) {
        int cc = tid >> 2, f4 = tid & 3;
        ((floatx4*)h_lds)[tid] = *(const floatx4*)&hin[(b * 64 + cc) * HW + p0 + f4 * 4];
    }
    // ---- s-projection B-frags -> registers (8 VGPR, once). Lane l holds
    // B[k=kc*32+q*8+j][n=s]; only col 0 (s==0) nonzero: B[k][0]=w_s[k].
    halfx8 sb0, sb1;
    #pragma unroll
    for (int j = 0; j < 8; ++j) { sb0[j] = (_Float16)0.0f; sb1[j] = (_Float16)0.0f; }
    if (s == 0) {
        floatx4 v0 = *(const floatx4*)&w_s[q * 8];
        floatx4 v1 = *(const floatx4*)&w_s[q * 8 + 4];
        floatx4 v2 = *(const floatx4*)&w_s[32 + q * 8];
        floatx4 v3 = *(const floatx4*)&w_s[32 + q * 8 + 4];
        #pragma unroll
        for (int j = 0; j < 4; ++j) {
            sb0[j]     = (_Float16)v0[j];
            sb0[4 + j] = (_Float16)v1[j];
            sb1[j]     = (_Float16)v2[j];
            sb1[4 + j] = (_Float16)v3[j];
        }
    }
    __syncthreads();

    // ---- conv_in (per wave, own group): x[g][t][px] = sum_c w_in[g8+t][c]*hin[c][px]+b_in
    // (w_in from global as floatx4; 16 px-lanes share addresses -> L1 broadcast)
    float* xs = xs_buf + g * 128;   // rows g*8+t
    {
        const float* hin_st = (const float*)h_lds;
        const floatx4* w0p = (const floatx4*)(w_in + (g * 8 + q) * 64);
        const floatx4* w1p = (const floatx4*)(w_in + (g * 8 + q + 4) * 64);
        floatx2 xacc; xacc.x = b_in[g * 8 + q]; xacc.y = b_in[g * 8 + q + 4];
        #pragma unroll 4
        for (int c4 = 0; c4 < 16; ++c4) {
            floatx4 wv0 = w0p[c4];
            floatx4 wv1 = w1p[c4];
            #pragma unroll
            for (int j = 0; j < 4; ++j) {
                float hv = hin_st[(c4 * 4 + j) * 16 + s];
                xacc.x += wv0[j] * hv;
                xacc.y += wv1[j] * hv;
            }
        }
        xs[q * 16 + s]       = xacc.x;
        xs[(q + 4) * 16 + s] = xacc.y;
    }
    __syncthreads();   // all hin reads complete before h zero
    // zero h state (4096 u32)
    #pragma unroll
    for (int i = 0; i < 8; ++i)
        ((unsigned*)h_lds)[tid + 512 * i] = 0u;
    __syncthreads();

    _Float16* hrow = h_lds + wv * 1024;   // 16 rows x 64 (swizzled)
    float bs = b_s_p[0];
    int sh8 = (s >> 1);                   // h-write 16B-block base
    int so4 = 4 * (s & 1);                // within-block offset

    // c-state, stored PRE-SCALED by 2*log2(e)
    float c_st[4][4];
    #pragma unroll
    for (int hb = 0; hb < 4; ++hb)
        #pragma unroll
        for (int r = 0; r < 4; ++r) c_st[hb][r] = 0.0f;

    for (int t = 0; t < TT; ++t) {
        // Memory barrier: forbids caching LDS (frags/wxb/x/h) in registers
        // across iterations (r7/r12: caching balloons regs past the cliff).
        asm volatile("" ::: "memory");

        // A-frags, swizzled: 16B-block (k>>3) XOR'd with row&7
        halfx8 a0 = *(const halfx8*)(hrow + s * 64 + 8 * (q ^ (s & 7)));
        halfx8 a1 = *(const halfx8*)(hrow + s * 64 + 8 * ((q + 4) ^ (s & 7)));

        // s_{t-1} = h_t @ w_s via MFMA (col 0 only); lanes s==0 hold seq q*4+r
        if (t > 0) {
            floatx4 sa = {0.f, 0.f, 0.f, 0.f};
            sa = __builtin_amdgcn_mfma_f32_16x16x32_f16(a0, sb0, sa, 0, 0, 0);
            sa = __builtin_amdgcn_mfma_f32_16x16x32_f16(a1, sb1, sa, 0, 0, 0);
            if (s == 0) {
                floatx4 o4 = {sa[0] + bs, sa[1] + bs, sa[2] + bs, sa[3] + bs};
                *(floatx4*)&xs[(t - 1) * 16 + q * 4] = o4;   // stile slot g*8+(t-1)
            }
        }

        floatx4 xv = *(const floatx4*)&xs[t * 16 + q * 4];
        floatx2 xlo; xlo.x = xv[0]; xlo.y = xv[1];
        floatx2 xhi; xhi.x = xv[2]; xhi.y = xv[3];

        halfx4 hpack[4];   // per-row packed h (hb-contiguous thanks to r11 perm)

        #pragma unroll
        for (int hb = 0; hb < 4; ++hb) {
            floatx4 acc[4];
            #pragma unroll
            for (int gi = 0; gi < 4; ++gi) {
                int nb = hb + 4 * gi;
                uh2 wb; wb.u = wxb_lds[s + 16 * nb];
                float wx = (float)wb.h[0];
                float bi = (float)wb.h[1];
                floatx2 lo = xlo * wx + bi;     // x*w_x + bias as C init
                floatx2 hi = xhi * wx + bi;
                floatx4 a = {lo.x, lo.y, hi.x, hi.y};
                halfx8 b0 = *(const halfx8*)&wfrag_lds[(nb * 2 + 0) * 64 + lane];
                halfx8 b1 = *(const halfx8*)&wfrag_lds[(nb * 2 + 1) * 64 + lane];
                a = __builtin_amdgcn_mfma_f32_16x16x32_f16(a0, b0, a, 0, 0, 0);
                a = __builtin_amdgcn_mfma_f32_16x16x32_f16(a1, b1, a, 0, 0, 0);
                acc[gi] = a;
            }
            #pragma unroll
            for (int p = 0; p < 2; ++p) {
                int r0 = 2 * p;
                // accs are pre-scaled: Ei=e^-i, Ef=e^-f, Eo=e^-o, Eg=e^{2g}
                floatx2 Ei; Ei.x = fast_exp2(acc[0][r0]); Ei.y = fast_exp2(acc[0][r0 + 1]);
                floatx2 Ef; Ef.x = fast_exp2(acc[1][r0]); Ef.y = fast_exp2(acc[1][r0 + 1]);
                floatx2 Eg; Eg.x = fast_exp2(acc[2][r0]); Eg.y = fast_exp2(acc[2][r0 + 1]);
                floatx2 Eo; Eo.x = fast_exp2(acc[3][r0]); Eo.y = fast_exp2(acc[3][r0 + 1]);
                floatx2 Bf  = Ef + 1.0f;
                floatx2 Pig = (Ei + 1.0f) * (Eg + 1.0f);
                floatx2 cp; cp.x = c_st[hb][r0]; cp.y = c_st[hb][r0 + 1];
                // cs' = f*cs + 2log2e * i*g  ==  [cs*Pig + SG*(Eg-1)*Bf] / (Bf*Pig)
                floatx2 num = cp * Pig + (Eg * SG - SG) * Bf;   // fma: SG*(Eg-1) exact
                floatx2 cs  = num * rcpx2(Bf * Pig);
                c_st[hb][r0] = cs.x; c_st[hb][r0 + 1] = cs.y;
                // h = o*tanh(c) = (Ec-1) / ((1+Eo)(1+Ec)),  Ec = exp2(cs) = e^{2c}
                floatx2 Ec  = exp2x2(cs);
                floatx2 hn  = (Ec - 1.0f) * rcpx2((Eo + 1.0f) * (Ec + 1.0f));
                hpack[r0 + 0][hb] = (_Float16)hn.x;
                hpack[r0 + 1][hb] = (_Float16)hn.y;
            }
        }
        // state for t+1: 4x ds_write_b64 at hid 4s..4s+3, rows q*4+r, swizzled
        {
            int rowb = q * 4;
            #pragma unroll
            for (int r = 0; r < 4; ++r) {
                int row = rowb + r;
                *(halfx4*)(hrow + row * 64 + 8 * (sh8 ^ (row & 7)) + so4) = hpack[r];
            }
        }
    }
    // final s_7 from h_8
    {
        asm volatile("" ::: "memory");
        halfx8 a0 = *(const halfx8*)(hrow + s * 64 + 8 * (q ^ (s & 7)));
        halfx8 a1 = *(const halfx8*)(hrow + s * 64 + 8 * ((q + 4) ^ (s & 7)));
        floatx4 sa = {0.f, 0.f, 0.f, 0.f};
        sa = __builtin_amdgcn_mfma_f32_16x16x32_f16(a0, sb0, sa, 0, 0, 0);
        sa = __builtin_amdgcn_mfma_f32_16x16x32_f16(a1, sb1, sa, 0, 0, 0);
        if (s == 0) {
            floatx4 o4 = {sa[0] + bs, sa[1] + bs, sa[2] + bs, sa[3] + bs};
            *(floatx4*)&xs[7 * 16 + q * 4] = o4;
        }
    }
    __syncthreads();   // all 64 stile channels ready

    // ---- conv_out epilogue: out[b][o][p0+px] = sum_c w_out[o][c]*stile[c][px] + b_out[o]
    // (w_out from global as floatx4; 16 px-lanes share addresses -> L1 broadcast)
    {
        int px = tid & 15;
        int oo = tid >> 4;                 // 0..31 -> outputs oo and oo+32
        floatx2 acc; acc.x = b_out[oo]; acc.y = b_out[oo + 32];
        #pragma unroll
        for (int c4 = 0; c4 < 16; ++c4) {
            floatx4 w0 = *(const floatx4*)&w_out[oo * 64 + c4 * 4];
            floatx4 w1 = *(const floatx4*)&w_out[(oo + 32) * 64 + c4 * 4];
            #pragma unroll
            for (int j = 0; j < 4; ++j) {
                float sv = xs_buf[(c4 * 4 + j) * 16 + px];
                acc.x += w0[j] * sv;
                acc.y += w1[j] * sv;
            }
        }
        out[(b * 64 + oo) * HW + p0 + px]      = acc.x;
        out[(b * 64 + oo + 32) * HW + p0 + px] = acc.y;
    }
}

extern "C" void kernel_launch(void* const* d_in, const int* in_sizes, int n_in,
                              void* d_out, int out_size, void* d_ws, size_t ws_size,
                              hipStream_t stream) {
    const float* h     = (const float*)d_in[0];
    const float* w_in  = (const float*)d_in[1];
    const float* b_in  = (const float*)d_in[2];
    const float* w_ih  = (const float*)d_in[3];
    const float* w_hh  = (const float*)d_in[4];
    const float* b_ih  = (const float*)d_in[5];
    const float* b_hh  = (const float*)d_in[6];
    const float* w_s   = (const float*)d_in[7];
    const float* b_s   = (const float*)d_in[8];
    const float* w_out = (const float*)d_in[9];
    const float* b_out = (const float*)d_in[10];
    float* out = (float*)d_out;
    float* ws  = (float*)d_ws;

    prep_kernel<<<9, 256, 0, stream>>>(w_ih, w_hh, b_ih, b_hh, ws);
    // fully fused conv_in + LSTM + conv_out: 2048 blocks x 512 threads.
    lstm_kernel<<<2048, 512, 0, stream>>>(h, ws, out, w_in, b_in, w_s, b_s,
                                          b_out, w_out);
}

// Round 11
// 229.817 us; speedup vs baseline: 1.0724x; 1.0100x over previous
//
#include <hip/hip_runtime.h>
#include <hip/hip_bf16.h>

// ---------------- problem constants ----------------
#define HW    4096      // H*W
#define BB    8         // batch
#define TT    8         // time steps

// ws layout (in floats)
constexpr int OFF_WFRAG = 0;                   // 32 frags * 64 lanes * 16B = 8192 floats
constexpr int OFF_WXB   = 8192;                // 256 u32 {w_x, bias} f16 pairs

// gate pre-scales folded into w_hh / w_x / bias at prep time:
//   i,f,o rows: * -log2(e)   -> sigmoid(x) = rcp(exp2(acc)+1)
//   g rows:     * 2*log2(e)  -> tanh(x) = (exp2(acc)-1)/(exp2(acc)+1)
constexpr float SI = -1.44269504088896340736f; // -log2(e)
constexpr float SG =  2.88539008177792681472f; // 2*log2(e)

typedef _Float16 halfx8 __attribute__((ext_vector_type(8)));
typedef _Float16 halfx4 __attribute__((ext_vector_type(4)));
typedef _Float16 halfx2 __attribute__((ext_vector_type(2)));
typedef float    floatx4 __attribute__((ext_vector_type(4)));
typedef float    floatx2 __attribute__((ext_vector_type(2)));

__device__ inline float fast_exp2(float x) {
#if __has_builtin(__builtin_amdgcn_exp2f)
    return __builtin_amdgcn_exp2f(x);
#else
    return __builtin_exp2f(x);
#endif
}
__device__ inline float fast_rcp(float x) {
#if __has_builtin(__builtin_amdgcn_rcpf)
    return __builtin_amdgcn_rcpf(x);
#else
    return 1.0f / x;
#endif
}
__device__ inline floatx2 exp2x2(floatx2 x) {
    floatx2 r; r.x = fast_exp2(x.x); r.y = fast_exp2(x.y); return r;
}
// r16: pairwise-batched reciprocal (1 v_rcp + 3 v_mul for 2 rcps); verified.
__device__ inline floatx2 rcpx2(floatx2 x) {
    float R = fast_rcp(x.x * x.y);
    floatx2 r; r.x = R * x.y; r.y = R * x.x; return r;
}
// r19: f16 dot-8 with f32 accumulate (v_dot2_f32_f16 when available).
__device__ inline float dot8f16(halfx8 a, halfx8 b, float acc) {
#if __has_builtin(__builtin_amdgcn_fdot2)
    #pragma unroll
    for (int j = 0; j < 4; ++j) {
        halfx2 av; av[0] = a[2 * j]; av[1] = a[2 * j + 1];
        halfx2 bv; bv[0] = b[2 * j]; bv[1] = b[2 * j + 1];
        acc = __builtin_amdgcn_fdot2(av, bv, acc, false);
    }
#else
    #pragma unroll
    for (int j = 0; j < 8; ++j) acc += (float)a[j] * (float)b[j];
#endif
    return acc;
}

union pack8 { _Float16 h[8]; uint4 u; };
union uh2   { unsigned u; _Float16 h[2]; };

// ---------------- prep: repack weights into d_ws (9 blocks) ----------------
// r9: activation pre-scales (SI/SG) folded in. r11: gate-column permutation
// (frag col sc of nb=(hb+4gi) holds gate 64*gi+4*sc+hb -> thread (s,hb)
// produces hid=4s+hb -> b64-packed h-writes). r18: wxb as f16 pairs.
__global__ __launch_bounds__(256) void prep_kernel(
    const float* __restrict__ w_ih,  const float* __restrict__ w_hh,
    const float* __restrict__ b_ih,  const float* __restrict__ b_hh,
    float* __restrict__ ws_f) {
    int tid = threadIdx.x;
    int bid = blockIdx.x;
    if (bid < 8) {
        int e = bid * 256 + tid;       // 0..2047
        uint4* wf = (uint4*)(ws_f + OFF_WFRAG);
        int l  = e & 63;
        int fi = e >> 6;
        int nb = fi >> 1, kc = fi & 1;
        int hb = nb & 3, gi = nb >> 2;
        int gate = gi * 64 + 4 * (l & 15) + hb;   // r11 permuted column
        int hid  = kc * 32 + (l >> 4) * 8;
        float sc = (gi == 2) ? SG : SI;
        const float* src = w_hh + gate * 64 + hid;
        pack8 p;
        #pragma unroll
        for (int j = 0; j < 8; ++j) p.h[j] = (_Float16)(src[j] * sc);
        wf[e] = p.u;
    } else {
        // {w_x, bias} f16 pairs, permuted + pre-scaled.
        int s_ = tid & 15, hb = (tid >> 4) & 3, gi = tid >> 6;
        int gate = gi * 64 + 4 * s_ + hb;
        float sc = (gi == 2) ? SG : SI;
        uh2 v;
        v.h[0] = (_Float16)(w_ih[gate] * sc);
        v.h[1] = (_Float16)((b_ih[gate] + b_hh[gate]) * sc);
        ((unsigned*)(ws_f + OFF_WXB))[tid] = v.u;
    }
}

// ---------------- fully fused conv_in + LSTM + conv_out ----------------
// Block = 512 threads = 8 waves = ONE 16-pixel tile x ALL 8 groups.
// r18 POST-MORTEM / occupancy model: reported VGPR_Count EXCLUDES the MFMA
// accumulator (AGPR) allocation in gfx950's unified file. Waves/CU is set by
// TOTAL regs: 24 waves (3 blocks) needs total <= 2048/6 = 85; 16 waves needs
// <= 128. r18 at reported 64 + ~24-40 acc fell in (85,128] -> stuck at 2
// blocks regardless of LDS diet. Also proven: LDS-traffic cuts at fixed TLP
// are worthless (r13->r18 removed 5.4M conflicts + traffic -> flat).
// r19: TEST the model by cutting ~12 total regs: s-projection MFMA replaced
// by v_dot2_f32_f16 dot (lane already holds h[s][k] in a0/a1; w_s staged as
// f16 in 128 B LDS, broadcast-read per t; 2x shfl_xor q-reduce). Deletes
// sb0/sb1 (-8 VGPR) and sa (-4 AGPR). Predicted total ~76-84 <= 85 ->
// 3 blocks/CU = 24 waves (+50% TLP on a ~64%-busy LDS pipe).
// LDS = 54400 B <= 163840/3 = 54613 -> 3 blocks/CU.
// Kill-criterion: occupancy stays <=45% -> model wrong, occupancy lane closed.
// asm clobber STAYS (r7/r12: reg-caching LDS crosses the VGPR cliff).
__global__ __launch_bounds__(512) void lstm_kernel(
    const float* __restrict__ hin,    // (B, 64, HW) original input h
    const float* __restrict__ ws_f,   // tables
    float* __restrict__ out,          // (B, 64, HW) final output
    const float* __restrict__ w_in,   // (64, 64)
    const float* __restrict__ b_in,   // (64,)
    const float* __restrict__ w_s,    // (1, 64)
    const float* __restrict__ b_s_p,  // (1,)
    const float* __restrict__ b_out,  // (64,)
    const float* __restrict__ w_out) {// (64, 64) [o][c]
    __shared__ uint4 wfrag_lds[2048];                  // 32768 B
    __shared__ unsigned wxb_lds[256];                  // 1024 B
    __shared__ __align__(16) float xs_buf[1024];       // 4096 B: [c=g*8+t][px16] x then s
    __shared__ __align__(16) _Float16 h_lds[8192];     // 16384 B: 8 waves x 16 x 64 swz
                                                       //          (front 4096 B: hin stage)
    __shared__ __align__(16) _Float16 ws16[64];        // 128 B: w_s as f16

    int tid = threadIdx.x;
    int ptile = blockIdx.x & 255;         // 256 tiles of 16 px
    int b     = blockIdx.x >> 8;
    int p0 = ptile * 16;

    int lane = tid & 63;
    int wv   = tid >> 6;                  // 0..7 == group g
    int g    = wv;
    int s    = lane & 15;                 // seq-local == pixel-local
    int q    = lane >> 4;

    // ---- stage weight fragments + wxb + w_s
    const uint4* wfg = (const uint4*)(ws_f + OFF_WFRAG);
    #pragma unroll
    for (int i = 0; i < 4; ++i)
        wfrag_lds[tid + 512 * i] = wfg[tid + 512 * i];
    if (tid < 256) wxb_lds[tid] = ((const unsigned*)(ws_f + OFF_WXB))[tid];
    if (tid < 64)  ws16[tid] = (_Float16)w_s[tid];
    // stage hin tile (64 ch x 16 px, f32) into h_lds front (dead until zeroed)
    if (tid < 256) {
        int cc = tid >> 2, f4 = tid & 3;
        ((floatx4*)h_lds)[tid] = *(const floatx4*)&hin[(b * 64 + cc) * HW + p0 + f4 * 4];
    }
    __syncthreads();

    // ---- conv_in (per wave, own group): x[g][t][px] = sum_c w_in[g8+t][c]*hin[c][px]+b_in
    // (w_in from global as floatx4; 16 px-lanes share addresses -> L1 broadcast)
    float* xs = xs_buf + g * 128;   // rows g*8+t
    {
        const float* hin_st = (const float*)h_lds;
        const floatx4* w0p = (const floatx4*)(w_in + (g * 8 + q) * 64);
        const floatx4* w1p = (const floatx4*)(w_in + (g * 8 + q + 4) * 64);
        floatx2 xacc; xacc.x = b_in[g * 8 + q]; xacc.y = b_in[g * 8 + q + 4];
        #pragma unroll 4
        for (int c4 = 0; c4 < 16; ++c4) {
            floatx4 wv0 = w0p[c4];
            floatx4 wv1 = w1p[c4];
            #pragma unroll
            for (int j = 0; j < 4; ++j) {
                float hv = hin_st[(c4 * 4 + j) * 16 + s];
                xacc.x += wv0[j] * hv;
                xacc.y += wv1[j] * hv;
            }
        }
        xs[q * 16 + s]       = xacc.x;
        xs[(q + 4) * 16 + s] = xacc.y;
    }
    __syncthreads();   // all hin reads complete before h zero
    // zero h state (4096 u32)
    #pragma unroll
    for (int i = 0; i < 8; ++i)
        ((unsigned*)h_lds)[tid + 512 * i] = 0u;
    __syncthreads();

    _Float16* hrow = h_lds + wv * 1024;   // 16 rows x 64 (swizzled)
    float bs = b_s_p[0];
    int sh8 = (s >> 1);                   // h-write 16B-block base
    int so4 = 4 * (s & 1);                // within-block offset

    // c-state, stored PRE-SCALED by 2*log2(e)
    float c_st[4][4];
    #pragma unroll
    for (int hb = 0; hb < 4; ++hb)
        #pragma unroll
        for (int r = 0; r < 4; ++r) c_st[hb][r] = 0.0f;

    for (int t = 0; t < TT; ++t) {
        // Memory barrier: forbids caching LDS (frags/wxb/x/h) in registers
        // across iterations (r7/r12: caching balloons regs past the cliff).
        asm volatile("" ::: "memory");

        // A-frags, swizzled: 16B-block (k>>3) XOR'd with row&7
        halfx8 a0 = *(const halfx8*)(hrow + s * 64 + 8 * (q ^ (s & 7)));
        halfx8 a1 = *(const halfx8*)(hrow + s * 64 + 8 * ((q + 4) ^ (s & 7)));

        // s_{t-1} = h_t . w_s via fdot2 (r19: was MFMA col-0; saves sb regs +
        // sa AGPRs). Lane (s,q) holds h[s][8q..8q+7], h[s][32+8q..+7] in
        // a0/a1; dot with w_s slices, then q-reduce via shfl_xor(16/32).
        if (t > 0) {
            halfx8 ws0 = *(const halfx8*)&ws16[q * 8];
            halfx8 ws1 = *(const halfx8*)&ws16[32 + q * 8];
            float sv = dot8f16(a1, ws1, dot8f16(a0, ws0, 0.0f));
            sv += __shfl_xor(sv, 16);
            sv += __shfl_xor(sv, 32);
            if (q == 0) xs[(t - 1) * 16 + s] = sv + bs;   // stile slot g*8+(t-1)
        }

        floatx4 xv = *(const floatx4*)&xs[t * 16 + q * 4];
        floatx2 xlo; xlo.x = xv[0]; xlo.y = xv[1];
        floatx2 xhi; xhi.x = xv[2]; xhi.y = xv[3];

        halfx4 hpack[4];   // per-row packed h (hb-contiguous thanks to r11 perm)

        #pragma unroll
        for (int hb = 0; hb < 4; ++hb) {
            floatx4 acc[4];
            #pragma unroll
            for (int gi = 0; gi < 4; ++gi) {
                int nb = hb + 4 * gi;
                uh2 wb; wb.u = wxb_lds[s + 16 * nb];
                float wx = (float)wb.h[0];
                float bi = (float)wb.h[1];
                floatx2 lo = xlo * wx + bi;     // x*w_x + bias as C init
                floatx2 hi = xhi * wx + bi;
                floatx4 a = {lo.x, lo.y, hi.x, hi.y};
                halfx8 b0 = *(const halfx8*)&wfrag_lds[(nb * 2 + 0) * 64 + lane];
                halfx8 b1 = *(const halfx8*)&wfrag_lds[(nb * 2 + 1) * 64 + lane];
                a = __builtin_amdgcn_mfma_f32_16x16x32_f16(a0, b0, a, 0, 0, 0);
                a = __builtin_amdgcn_mfma_f32_16x16x32_f16(a1, b1, a, 0, 0, 0);
                acc[gi] = a;
            }
            #pragma unroll
            for (int p = 0; p < 2; ++p) {
                int r0 = 2 * p;
                // accs are pre-scaled: Ei=e^-i, Ef=e^-f, Eo=e^-o, Eg=e^{2g}
                floatx2 Ei; Ei.x = fast_exp2(acc[0][r0]); Ei.y = fast_exp2(acc[0][r0 + 1]);
                floatx2 Ef; Ef.x = fast_exp2(acc[1][r0]); Ef.y = fast_exp2(acc[1][r0 + 1]);
                floatx2 Eg; Eg.x = fast_exp2(acc[2][r0]); Eg.y = fast_exp2(acc[2][r0 + 1]);
                floatx2 Eo; Eo.x = fast_exp2(acc[3][r0]); Eo.y = fast_exp2(acc[3][r0 + 1]);
                floatx2 Bf  = Ef + 1.0f;
                floatx2 Pig = (Ei + 1.0f) * (Eg + 1.0f);
                floatx2 cp; cp.x = c_st[hb][r0]; cp.y = c_st[hb][r0 + 1];
                // cs' = f*cs + 2log2e * i*g  ==  [cs*Pig + SG*(Eg-1)*Bf] / (Bf*Pig)
                floatx2 num = cp * Pig + (Eg * SG - SG) * Bf;   // fma: SG*(Eg-1) exact
                floatx2 cs  = num * rcpx2(Bf * Pig);
                c_st[hb][r0] = cs.x; c_st[hb][r0 + 1] = cs.y;
                // h = o*tanh(c) = (Ec-1) / ((1+Eo)(1+Ec)),  Ec = exp2(cs) = e^{2c}
                floatx2 Ec  = exp2x2(cs);
                floatx2 hn  = (Ec - 1.0f) * rcpx2((Eo + 1.0f) * (Ec + 1.0f));
                hpack[r0 + 0][hb] = (_Float16)hn.x;
                hpack[r0 + 1][hb] = (_Float16)hn.y;
            }
        }
        // state for t+1: 4x ds_write_b64 at hid 4s..4s+3, rows q*4+r, swizzled
        {
            int rowb = q * 4;
            #pragma unroll
            for (int r = 0; r < 4; ++r) {
                int row = rowb + r;
                *(halfx4*)(hrow + row * 64 + 8 * (sh8 ^ (row & 7)) + so4) = hpack[r];
            }
        }
    }
    // final s_7 from h_8
    {
        asm volatile("" ::: "memory");
        halfx8 a0 = *(const halfx8*)(hrow + s * 64 + 8 * (q ^ (s & 7)));
        halfx8 a1 = *(const halfx8*)(hrow + s * 64 + 8 * ((q + 4) ^ (s & 7)));
        halfx8 ws0 = *(const halfx8*)&ws16[q * 8];
        halfx8 ws1 = *(const halfx8*)&ws16[32 + q * 8];
        float sv = dot8f16(a1, ws1, dot8f16(a0, ws0, 0.0f));
        sv += __shfl_xor(sv, 16);
        sv += __shfl_xor(sv, 32);
        if (q == 0) xs[7 * 16 + s] = sv + bs;
    }
    __syncthreads();   // all 64 stile channels ready

    // ---- conv_out epilogue: out[b][o][p0+px] = sum_c w_out[o][c]*stile[c][px] + b_out[o]
    // (w_out from global as floatx4; 16 px-lanes share addresses -> L1 broadcast)
    {
        int px = tid & 15;
        int oo = tid >> 4;                 // 0..31 -> outputs oo and oo+32
        floatx2 acc; acc.x = b_out[oo]; acc.y = b_out[oo + 32];
        #pragma unroll
        for (int c4 = 0; c4 < 16; ++c4) {
            floatx4 w0 = *(const floatx4*)&w_out[oo * 64 + c4 * 4];
            floatx4 w1 = *(const floatx4*)&w_out[(oo + 32) * 64 + c4 * 4];
            #pragma unroll
            for (int j = 0; j < 4; ++j) {
                float sv = xs_buf[(c4 * 4 + j) * 16 + px];
                acc.x += w0[j] * sv;
                acc.y += w1[j] * sv;
            }
        }
        out[(b * 64 + oo) * HW + p0 + px]      = acc.x;
        out[(b * 64 + oo + 32) * HW + p0 + px] = acc.y;
    }
}

extern "C" void kernel_launch(void* const* d_in, const int* in_sizes, int n_in,
                              void* d_out, int out_size, void* d_ws, size_t ws_size,
                              hipStream_t stream) {
    const float* h     = (const float*)d_in[0];
    const float* w_in  = (const float*)d_in[1];
    const float* b_in  = (const float*)d_in[2];
    const float* w_ih  = (const float*)d_in[3];
    const float* w_hh  = (const float*)d_in[4];
    const float* b_ih  = (const float*)d_in[5];
    const float* b_hh  = (const float*)d_in[6];
    const float* w_s   = (const float*)d_in[7];
    const float* b_s   = (const float*)d_in[8];
    const float* w_out = (const float*)d_in[9];
    const float* b_out = (const float*)d_in[10];
    float* out = (float*)d_out;
    float* ws  = (float*)d_ws;

    prep_kernel<<<9, 256, 0, stream>>>(w_ih, w_hh, b_ih, b_hh, ws);
    // fully fused conv_in + LSTM + conv_out: 2048 blocks x 512 threads.
    lstm_kernel<<<2048, 512, 0, stream>>>(h, ws, out, w_in, b_in, w_s, b_s,
                                          b_out, w_out);
}